// Round 1
// baseline (1193.582 us; speedup 1.0000x reference)
//
#include <hip/hip_runtime.h>
#include <hip/hip_bf16.h>

#define MT 32
#define EPSV 1e-5f

typedef __attribute__((ext_vector_type(8))) short short8;
typedef __attribute__((ext_vector_type(4))) float floatx4;

__device__ __forceinline__ unsigned short f2bf(float f) {
    unsigned u = __builtin_bit_cast(unsigned, f);
    u += 0x7fff + ((u >> 16) & 1);
    return (unsigned short)(u >> 16);
}
__device__ __forceinline__ float bf2f(short s) {
    unsigned u = ((unsigned)(unsigned short)s) << 16;
    return __builtin_bit_cast(float, u);
}

// ws layout (shorts): w1t [512][64] at 0, w2t [512][512] at 32768, wh1t [256][512] at 294912
__global__ void convert_weights(const float* __restrict__ W1, const float* __restrict__ W2,
                                const float* __restrict__ Wh1, short* __restrict__ ws) {
    int idx = blockIdx.x * 256 + threadIdx.x;
    if (idx < 32768) {
        int n = idx >> 6, k = idx & 63;                      // w1t[n][k] = W1[k][n]
        ws[idx] = (short)f2bf(W1[k * 512 + n]);
    } else if (idx < 32768 + 262144) {
        int j = idx - 32768;
        int n = j >> 9, k = j & 511;                         // w2t[n][k] = W2[k][n]
        ws[idx] = (short)f2bf(W2[k * 512 + n]);
    } else if (idx < 32768 + 262144 + 131072) {
        int j = idx - (32768 + 262144);
        int n = j >> 9, h = j & 511;                         // wh1t[n=kk*64+d][h] = Wh1[kk][h][d]
        int kk = n >> 6, d = n & 63;
        ws[idx] = (short)f2bf(Wh1[(kk * 512 + h) * 64 + d]);
    }
}

// LN + leaky in place on a [32][512] bf16 LDS tile (XOR-swizzled in 8-elem blocks)
__device__ __forceinline__ void layernorm_leaky(short* h, const float* __restrict__ g,
                                                const float* __restrict__ be, int tid) {
    int r = tid >> 3, is = tid & 7;
    float sum = 0.f, sq = 0.f;
#pragma unroll
    for (int jj = 0; jj < 8; jj++) {
        int cb = jj * 8 + is;
        int idx = r * 512 + ((cb ^ (r & 7)) << 3);
        short8 v = *(short8*)&h[idx];
#pragma unroll
        for (int e = 0; e < 8; e++) { float f = bf2f(v[e]); sum += f; sq += f * f; }
    }
#pragma unroll
    for (int off = 1; off < 8; off <<= 1) {
        sum += __shfl_xor(sum, off, 64);
        sq  += __shfl_xor(sq,  off, 64);
    }
    float mean = sum * (1.f / 512.f);
    float var  = sq * (1.f / 512.f) - mean * mean;
    float rstd = rsqrtf(var + EPSV);
#pragma unroll
    for (int jj = 0; jj < 8; jj++) {
        int cb = jj * 8 + is;
        int c0 = cb * 8;
        int idx = r * 512 + ((cb ^ (r & 7)) << 3);
        short8 v = *(short8*)&h[idx];
        floatx4 ga = *(const floatx4*)(g + c0);
        floatx4 gb = *(const floatx4*)(g + c0 + 4);
        floatx4 ba = *(const floatx4*)(be + c0);
        floatx4 bb = *(const floatx4*)(be + c0 + 4);
#pragma unroll
        for (int e = 0; e < 8; e++) {
            float f = (bf2f(v[e]) - mean) * rstd;
            float gg = (e < 4) ? ga[e] : gb[e - 4];
            float bt = (e < 4) ? ba[e] : bb[e - 4];
            f = f * gg + bt;
            f = (f >= 0.f) ? f : 0.2f * f;
            v[e] = (short)f2bf(f);
        }
        *(short8*)&h[idx] = v;
    }
}

__global__ __launch_bounds__(256) void fused_kernel(
    const float* __restrict__ z, const int* __restrict__ x, const int* __restrict__ y,
    const float* __restrict__ b1, const float* __restrict__ g1, const float* __restrict__ be1,
    const float* __restrict__ b2, const float* __restrict__ g2, const float* __restrict__ be2,
    const float* __restrict__ bh1, const float* __restrict__ Wh2, const float* __restrict__ bh2,
    const short* __restrict__ ws, float* __restrict__ out)
{
    __shared__ short lds_h1[MT * 512];
    __shared__ short lds_h2[MT * 512];

    const short* w1t  = ws;
    const short* w2t  = ws + 32768;
    const short* wh1t = ws + 32768 + 262144;

    int tid  = threadIdx.x;
    int wave = tid >> 6;
    int lane = tid & 63;
    int quad = lane >> 4;
    int l16  = lane & 15;
    int blk0 = blockIdx.x * MT;
    int nslab = wave * 128;

    // ---------- stage 1: h1 = z @ W1 + b1 ----------
    floatx4 acc[2][8];
#pragma unroll
    for (int mt = 0; mt < 2; mt++)
#pragma unroll
        for (int nt = 0; nt < 8; nt++) acc[mt][nt] = (floatx4){0.f, 0.f, 0.f, 0.f};

#pragma unroll
    for (int ks = 0; ks < 2; ks++) {
        short8 afr[2];
#pragma unroll
        for (int mt = 0; mt < 2; mt++) {
            int row = blk0 + mt * 16 + l16;
            const float* zp = z + row * 64 + ks * 32 + quad * 8;
            floatx4 f0 = *(const floatx4*)zp;
            floatx4 f1 = *(const floatx4*)(zp + 4);
            short8 a;
            a[0] = (short)f2bf(f0[0]); a[1] = (short)f2bf(f0[1]);
            a[2] = (short)f2bf(f0[2]); a[3] = (short)f2bf(f0[3]);
            a[4] = (short)f2bf(f1[0]); a[5] = (short)f2bf(f1[1]);
            a[6] = (short)f2bf(f1[2]); a[7] = (short)f2bf(f1[3]);
            afr[mt] = a;
        }
#pragma unroll
        for (int nt = 0; nt < 8; nt++) {
            const short* bp = w1t + (nslab + nt * 16 + l16) * 64 + ks * 32 + quad * 8;
            short8 b = *(const short8*)bp;
            acc[0][nt] = __builtin_amdgcn_mfma_f32_16x16x32_bf16(afr[0], b, acc[0][nt], 0, 0, 0);
            acc[1][nt] = __builtin_amdgcn_mfma_f32_16x16x32_bf16(afr[1], b, acc[1][nt], 0, 0, 0);
        }
    }
#pragma unroll
    for (int mt = 0; mt < 2; mt++)
#pragma unroll
        for (int nt = 0; nt < 8; nt++) {
            int col = nslab + nt * 16 + l16;
            float bias = b1[col];
#pragma unroll
            for (int r2 = 0; r2 < 4; r2++) {
                int row = mt * 16 + quad * 4 + r2;
                lds_h1[row * 512 + (((col >> 3) ^ (row & 7)) << 3) + (col & 7)] =
                    (short)f2bf(acc[mt][nt][r2] + bias);
            }
        }
    __syncthreads();
    layernorm_leaky(lds_h1, g1, be1, tid);
    __syncthreads();

    // ---------- stage 2: h2 = h1 @ W2 + b2 ----------
#pragma unroll
    for (int mt = 0; mt < 2; mt++)
#pragma unroll
        for (int nt = 0; nt < 8; nt++) acc[mt][nt] = (floatx4){0.f, 0.f, 0.f, 0.f};

    for (int ks = 0; ks < 16; ks++) {
        short8 afr[2];
#pragma unroll
        for (int mt = 0; mt < 2; mt++) {
            int row = mt * 16 + l16;
            int cb = ks * 4 + quad;
            afr[mt] = *(short8*)&lds_h1[row * 512 + ((cb ^ (row & 7)) << 3)];
        }
#pragma unroll
        for (int nt = 0; nt < 8; nt++) {
            const short* bp = w2t + (nslab + nt * 16 + l16) * 512 + ks * 32 + quad * 8;
            short8 b = *(const short8*)bp;
            acc[0][nt] = __builtin_amdgcn_mfma_f32_16x16x32_bf16(afr[0], b, acc[0][nt], 0, 0, 0);
            acc[1][nt] = __builtin_amdgcn_mfma_f32_16x16x32_bf16(afr[1], b, acc[1][nt], 0, 0, 0);
        }
    }
#pragma unroll
    for (int mt = 0; mt < 2; mt++)
#pragma unroll
        for (int nt = 0; nt < 8; nt++) {
            int col = nslab + nt * 16 + l16;
            float bias = b2[col];
#pragma unroll
            for (int r2 = 0; r2 < 4; r2++) {
                int row = mt * 16 + quad * 4 + r2;
                lds_h2[row * 512 + (((col >> 3) ^ (row & 7)) << 3) + (col & 7)] =
                    (short)f2bf(acc[mt][nt][r2] + bias);
            }
        }
    __syncthreads();
    layernorm_leaky(lds_h2, g2, be2, tid);
    __syncthreads();

    // ---------- stage 3: t[k] = relu(h2 @ Wh1[k] + bh1[k]) for all 4 heads ----------
    floatx4 acc3[2][4];
#pragma unroll
    for (int mt = 0; mt < 2; mt++)
#pragma unroll
        for (int nt = 0; nt < 4; nt++) acc3[mt][nt] = (floatx4){0.f, 0.f, 0.f, 0.f};

    for (int ks = 0; ks < 16; ks++) {
        short8 afr[2];
#pragma unroll
        for (int mt = 0; mt < 2; mt++) {
            int row = mt * 16 + l16;
            int cb = ks * 4 + quad;
            afr[mt] = *(short8*)&lds_h2[row * 512 + ((cb ^ (row & 7)) << 3)];
        }
#pragma unroll
        for (int nt = 0; nt < 4; nt++) {
            const short* bp = wh1t + (wave * 64 + nt * 16 + l16) * 512 + ks * 32 + quad * 8;
            short8 b = *(const short8*)bp;
            acc3[0][nt] = __builtin_amdgcn_mfma_f32_16x16x32_bf16(afr[0], b, acc3[0][nt], 0, 0, 0);
            acc3[1][nt] = __builtin_amdgcn_mfma_f32_16x16x32_bf16(afr[1], b, acc3[1][nt], 0, 0, 0);
        }
    }
    // t tile into lds_h1 (free now), row-major stride 264
    short* lds_t = lds_h1;
#pragma unroll
    for (int mt = 0; mt < 2; mt++)
#pragma unroll
        for (int nt = 0; nt < 4; nt++) {
            int col = wave * 64 + nt * 16 + l16;   // col = kk*64 + d
            float bias = bh1[col];
#pragma unroll
            for (int r2 = 0; r2 < 4; r2++) {
                int row = mt * 16 + quad * 4 + r2;
                float v = acc3[mt][nt][r2] + bias;
                v = (v > 0.f) ? v : 0.f;
                lds_t[row * 264 + col] = (short)f2bf(v);
            }
        }
    __syncthreads();

    // ---------- stage 4: per-row head select, logits, softmax ----------
    {
        int r = tid >> 3, is = tid & 7;
        int grow = blk0 + r;
        int kk = 2 * x[grow] + y[grow];
        short8 t8 = *(short8*)&lds_t[r * 264 + kk * 64 + is * 8];
        const float* wp = Wh2 + kk * 256 + is * 32;
        float lg0 = 0.f, lg1 = 0.f, lg2 = 0.f, lg3 = 0.f;
#pragma unroll
        for (int dd = 0; dd < 8; dd++) {
            float td = bf2f(t8[dd]);
            floatx4 wv = *(const floatx4*)(wp + dd * 4);
            lg0 += td * wv[0]; lg1 += td * wv[1]; lg2 += td * wv[2]; lg3 += td * wv[3];
        }
#pragma unroll
        for (int off = 1; off < 8; off <<= 1) {
            lg0 += __shfl_xor(lg0, off, 64);
            lg1 += __shfl_xor(lg1, off, 64);
            lg2 += __shfl_xor(lg2, off, 64);
            lg3 += __shfl_xor(lg3, off, 64);
        }
        if (is == 0) {
            lg0 += bh2[kk * 4 + 0]; lg1 += bh2[kk * 4 + 1];
            lg2 += bh2[kk * 4 + 2]; lg3 += bh2[kk * 4 + 3];
            float m = fmaxf(fmaxf(lg0, lg1), fmaxf(lg2, lg3));
            float e0 = __expf(lg0 - m), e1 = __expf(lg1 - m);
            float e2 = __expf(lg2 - m), e3 = __expf(lg3 - m);
            float inv = 1.f / (e0 + e1 + e2 + e3);
            floatx4 o = {e0 * inv, e1 * inv, e2 * inv, e3 * inv};
            *(floatx4*)(out + grow * 4) = o;
        }
    }
}

extern "C" void kernel_launch(void* const* d_in, const int* in_sizes, int n_in,
                              void* d_out, int out_size, void* d_ws, size_t ws_size,
                              hipStream_t stream) {
    const float* z   = (const float*)d_in[0];
    const int*   x   = (const int*)d_in[1];
    const int*   y   = (const int*)d_in[2];
    const float* W1  = (const float*)d_in[3];
    const float* b1  = (const float*)d_in[4];
    const float* g1  = (const float*)d_in[5];
    const float* be1 = (const float*)d_in[6];
    const float* W2  = (const float*)d_in[7];
    const float* b2  = (const float*)d_in[8];
    const float* g2  = (const float*)d_in[9];
    const float* be2 = (const float*)d_in[10];
    const float* Wh1 = (const float*)d_in[11];
    const float* bh1 = (const float*)d_in[12];
    const float* Wh2 = (const float*)d_in[13];
    const float* bh2 = (const float*)d_in[14];
    short* ws = (short*)d_ws;
    float* out = (float*)d_out;

    hipLaunchKernelGGL(convert_weights, dim3(1664), dim3(256), 0, stream, W1, W2, Wh1, ws);
    hipLaunchKernelGGL(fused_kernel, dim3(262144 / MT), dim3(256), 0, stream,
                       z, x, y, b1, g1, be1, b2, g2, be2, bh1, Wh2, bh2,
                       (const short*)ws, out);
}

// Round 2
// 1149.196 us; speedup vs baseline: 1.0386x; 1.0386x over previous
//
#include <hip/hip_runtime.h>
#include <hip/hip_bf16.h>

#define MT 32
#define EPSV 1e-5f

typedef __attribute__((ext_vector_type(8))) short short8;
typedef __attribute__((ext_vector_type(4))) float floatx4;
typedef __attribute__((ext_vector_type(2))) float floatx2;

__device__ __forceinline__ unsigned short f2bf(float f) {
    unsigned u = __builtin_bit_cast(unsigned, f);
    u += 0x7fff + ((u >> 16) & 1);
    return (unsigned short)(u >> 16);
}
__device__ __forceinline__ float bf2f(short s) {
    unsigned u = ((unsigned)(unsigned short)s) << 16;
    return __builtin_bit_cast(float, u);
}

// ws layout (shorts): w1t [512][64] at 0, w2t [512][512] at 32768, wh1t [256][512] at 294912
__global__ void convert_weights(const float* __restrict__ W1, const float* __restrict__ W2,
                                const float* __restrict__ Wh1, short* __restrict__ ws) {
    int idx = blockIdx.x * 256 + threadIdx.x;
    if (idx < 32768) {
        int n = idx >> 6, k = idx & 63;                      // w1t[n][k] = W1[k][n]
        ws[idx] = (short)f2bf(W1[k * 512 + n]);
    } else if (idx < 32768 + 262144) {
        int j = idx - 32768;
        int n = j >> 9, k = j & 511;                         // w2t[n][k] = W2[k][n]
        ws[idx] = (short)f2bf(W2[k * 512 + n]);
    } else if (idx < 32768 + 262144 + 131072) {
        int j = idx - (32768 + 262144);
        int n = j >> 9, h = j & 511;                         // wh1t[n=kk*64+d][h] = Wh1[kk][h][d]
        int kk = n >> 6, d = n & 63;
        ws[idx] = (short)f2bf(Wh1[(kk * 512 + h) * 64 + d]);
    }
}

// swizzled LDS address for a [32][512] bf16 tile (b128-read conflict-free)
__device__ __forceinline__ int sw(int row, int col) {
    return row * 512 + (((col >> 3) ^ (row & 7)) << 3) + (col & 7);
}

__global__ __launch_bounds__(256, 4) void fused_kernel(
    const float* __restrict__ z, const int* __restrict__ x, const int* __restrict__ y,
    const float* __restrict__ b1, const float* __restrict__ g1, const float* __restrict__ be1,
    const float* __restrict__ b2, const float* __restrict__ g2, const float* __restrict__ be2,
    const float* __restrict__ bh1, const float* __restrict__ Wh2, const float* __restrict__ bh2,
    const short* __restrict__ ws, float* __restrict__ out)
{
    __shared__ short tile[MT * 512];      // 32 KB, reused: h1 -> h2 -> t
    __shared__ float pstats[MT][8];       // [row][wave*2 + {sum,sq}]
    __shared__ floatx2 rstats[MT];        // {mean, rstd}

    const short* w1t  = ws;
    const short* w2t  = ws + 32768;
    const short* wh1t = ws + 32768 + 262144;

    int tid  = threadIdx.x;
    int wave = tid >> 6;
    int lane = tid & 63;
    int quad = lane >> 4;
    int l16  = lane & 15;
    int blk0 = blockIdx.x * MT;
    int nslab = wave * 128;

    floatx4 acc[2][8];

    // ================= stage 1: h1 = LN(z @ W1 + b1) -> leaky =================
#pragma unroll
    for (int mt = 0; mt < 2; mt++)
#pragma unroll
        for (int nt = 0; nt < 8; nt++) acc[mt][nt] = (floatx4){0.f, 0.f, 0.f, 0.f};

#pragma unroll
    for (int ks = 0; ks < 2; ks++) {
        short8 afr[2];
#pragma unroll
        for (int mt = 0; mt < 2; mt++) {
            int row = blk0 + mt * 16 + l16;
            const float* zp = z + row * 64 + ks * 32 + quad * 8;
            floatx4 f0 = *(const floatx4*)zp;
            floatx4 f1 = *(const floatx4*)(zp + 4);
            short8 a;
            a[0] = (short)f2bf(f0[0]); a[1] = (short)f2bf(f0[1]);
            a[2] = (short)f2bf(f0[2]); a[3] = (short)f2bf(f0[3]);
            a[4] = (short)f2bf(f1[0]); a[5] = (short)f2bf(f1[1]);
            a[6] = (short)f2bf(f1[2]); a[7] = (short)f2bf(f1[3]);
            afr[mt] = a;
        }
#pragma unroll
        for (int nt = 0; nt < 8; nt++) {
            const short* bp = w1t + (nslab + nt * 16 + l16) * 64 + ks * 32 + quad * 8;
            short8 b = *(const short8*)bp;
            acc[0][nt] = __builtin_amdgcn_mfma_f32_16x16x32_bf16(afr[0], b, acc[0][nt], 0, 0, 0);
            acc[1][nt] = __builtin_amdgcn_mfma_f32_16x16x32_bf16(afr[1], b, acc[1][nt], 0, 0, 0);
        }
    }

    // bias + in-register LN stats
    {
#pragma unroll
        for (int nt = 0; nt < 8; nt++) {
            float bv = b1[nslab + nt * 16 + l16];
#pragma unroll
            for (int mt = 0; mt < 2; mt++)
#pragma unroll
                for (int r2 = 0; r2 < 4; r2++) acc[mt][nt][r2] += bv;
        }
        float sum[2][4] = {}, sq[2][4] = {};
#pragma unroll
        for (int mt = 0; mt < 2; mt++)
#pragma unroll
            for (int nt = 0; nt < 8; nt++)
#pragma unroll
                for (int r2 = 0; r2 < 4; r2++) {
                    float v = acc[mt][nt][r2];
                    sum[mt][r2] += v; sq[mt][r2] += v * v;
                }
#pragma unroll
        for (int m = 1; m < 16; m <<= 1)
#pragma unroll
            for (int mt = 0; mt < 2; mt++)
#pragma unroll
                for (int r2 = 0; r2 < 4; r2++) {
                    sum[mt][r2] += __shfl_xor(sum[mt][r2], m, 64);
                    sq[mt][r2]  += __shfl_xor(sq[mt][r2],  m, 64);
                }
        if (l16 == 0) {
#pragma unroll
            for (int mt = 0; mt < 2; mt++)
#pragma unroll
                for (int r2 = 0; r2 < 4; r2++) {
                    int row = mt * 16 + quad * 4 + r2;
                    *(floatx2*)&pstats[row][wave * 2] = (floatx2){sum[mt][r2], sq[mt][r2]};
                }
        }
    }
    __syncthreads();
    if (tid < MT) {
        float s = pstats[tid][0] + pstats[tid][2] + pstats[tid][4] + pstats[tid][6];
        float q = pstats[tid][1] + pstats[tid][3] + pstats[tid][5] + pstats[tid][7];
        float mean = s * (1.f / 512.f);
        float var  = q * (1.f / 512.f) - mean * mean;
        rstats[tid] = (floatx2){mean, rsqrtf(var + EPSV)};
    }
    __syncthreads();
    {
        floatx2 st[2][4];
#pragma unroll
        for (int mt = 0; mt < 2; mt++)
#pragma unroll
            for (int r2 = 0; r2 < 4; r2++) st[mt][r2] = rstats[mt * 16 + quad * 4 + r2];
#pragma unroll
        for (int nt = 0; nt < 8; nt++) {
            int col = nslab + nt * 16 + l16;
            float gv = g1[col], bev = be1[col];
#pragma unroll
            for (int mt = 0; mt < 2; mt++)
#pragma unroll
                for (int r2 = 0; r2 < 4; r2++) {
                    int row = mt * 16 + quad * 4 + r2;
                    float f = (acc[mt][nt][r2] - st[mt][r2][0]) * st[mt][r2][1] * gv + bev;
                    f = (f >= 0.f) ? f : 0.2f * f;
                    tile[sw(row, col)] = (short)f2bf(f);
                }
        }
    }
    __syncthreads();

    // ================= stage 2: h2 = LN(h1 @ W2 + b2) -> leaky =================
#pragma unroll
    for (int mt = 0; mt < 2; mt++)
#pragma unroll
        for (int nt = 0; nt < 8; nt++) acc[mt][nt] = (floatx4){0.f, 0.f, 0.f, 0.f};

    for (int ks = 0; ks < 16; ks++) {
        short8 afr[2];
#pragma unroll
        for (int mt = 0; mt < 2; mt++) {
            int row = mt * 16 + l16;
            int cb = ks * 4 + quad;
            afr[mt] = *(short8*)&tile[row * 512 + ((cb ^ (row & 7)) << 3)];
        }
#pragma unroll
        for (int nt = 0; nt < 8; nt++) {
            const short* bp = w2t + (nslab + nt * 16 + l16) * 512 + ks * 32 + quad * 8;
            short8 b = *(const short8*)bp;
            acc[0][nt] = __builtin_amdgcn_mfma_f32_16x16x32_bf16(afr[0], b, acc[0][nt], 0, 0, 0);
            acc[1][nt] = __builtin_amdgcn_mfma_f32_16x16x32_bf16(afr[1], b, acc[1][nt], 0, 0, 0);
        }
    }
    {
#pragma unroll
        for (int nt = 0; nt < 8; nt++) {
            float bv = b2[nslab + nt * 16 + l16];
#pragma unroll
            for (int mt = 0; mt < 2; mt++)
#pragma unroll
                for (int r2 = 0; r2 < 4; r2++) acc[mt][nt][r2] += bv;
        }
        float sum[2][4] = {}, sq[2][4] = {};
#pragma unroll
        for (int mt = 0; mt < 2; mt++)
#pragma unroll
            for (int nt = 0; nt < 8; nt++)
#pragma unroll
                for (int r2 = 0; r2 < 4; r2++) {
                    float v = acc[mt][nt][r2];
                    sum[mt][r2] += v; sq[mt][r2] += v * v;
                }
#pragma unroll
        for (int m = 1; m < 16; m <<= 1)
#pragma unroll
            for (int mt = 0; mt < 2; mt++)
#pragma unroll
                for (int r2 = 0; r2 < 4; r2++) {
                    sum[mt][r2] += __shfl_xor(sum[mt][r2], m, 64);
                    sq[mt][r2]  += __shfl_xor(sq[mt][r2],  m, 64);
                }
        if (l16 == 0) {
#pragma unroll
            for (int mt = 0; mt < 2; mt++)
#pragma unroll
                for (int r2 = 0; r2 < 4; r2++) {
                    int row = mt * 16 + quad * 4 + r2;
                    *(floatx2*)&pstats[row][wave * 2] = (floatx2){sum[mt][r2], sq[mt][r2]};
                }
        }
    }
    __syncthreads();
    if (tid < MT) {
        float s = pstats[tid][0] + pstats[tid][2] + pstats[tid][4] + pstats[tid][6];
        float q = pstats[tid][1] + pstats[tid][3] + pstats[tid][5] + pstats[tid][7];
        float mean = s * (1.f / 512.f);
        float var  = q * (1.f / 512.f) - mean * mean;
        rstats[tid] = (floatx2){mean, rsqrtf(var + EPSV)};
    }
    __syncthreads();
    {
        floatx2 st[2][4];
#pragma unroll
        for (int mt = 0; mt < 2; mt++)
#pragma unroll
            for (int r2 = 0; r2 < 4; r2++) st[mt][r2] = rstats[mt * 16 + quad * 4 + r2];
#pragma unroll
        for (int nt = 0; nt < 8; nt++) {
            int col = nslab + nt * 16 + l16;
            float gv = g2[col], bev = be2[col];
#pragma unroll
            for (int mt = 0; mt < 2; mt++)
#pragma unroll
                for (int r2 = 0; r2 < 4; r2++) {
                    int row = mt * 16 + quad * 4 + r2;
                    float f = (acc[mt][nt][r2] - st[mt][r2][0]) * st[mt][r2][1] * gv + bev;
                    f = (f >= 0.f) ? f : 0.2f * f;
                    tile[sw(row, col)] = (short)f2bf(f);
                }
        }
    }
    __syncthreads();

    // ================= stage 3: t[k] = relu(h2 @ Wh1[k] + bh1[k]), all 4 heads =================
    floatx4 acc3[2][4];
#pragma unroll
    for (int mt = 0; mt < 2; mt++)
#pragma unroll
        for (int nt = 0; nt < 4; nt++) acc3[mt][nt] = (floatx4){0.f, 0.f, 0.f, 0.f};

    for (int ks = 0; ks < 16; ks++) {
        short8 afr[2];
#pragma unroll
        for (int mt = 0; mt < 2; mt++) {
            int row = mt * 16 + l16;
            int cb = ks * 4 + quad;
            afr[mt] = *(short8*)&tile[row * 512 + ((cb ^ (row & 7)) << 3)];
        }
#pragma unroll
        for (int nt = 0; nt < 4; nt++) {
            const short* bp = wh1t + (wave * 64 + nt * 16 + l16) * 512 + ks * 32 + quad * 8;
            short8 b = *(const short8*)bp;
            acc3[0][nt] = __builtin_amdgcn_mfma_f32_16x16x32_bf16(afr[0], b, acc3[0][nt], 0, 0, 0);
            acc3[1][nt] = __builtin_amdgcn_mfma_f32_16x16x32_bf16(afr[1], b, acc3[1][nt], 0, 0, 0);
        }
    }
    __syncthreads();   // all stage-3 tile reads done before t overwrites it
#pragma unroll
    for (int mt = 0; mt < 2; mt++)
#pragma unroll
        for (int nt = 0; nt < 4; nt++) {
            int col = wave * 64 + nt * 16 + l16;   // col = kk*64 + d
            float bias = bh1[col];
#pragma unroll
            for (int r2 = 0; r2 < 4; r2++) {
                int row = mt * 16 + quad * 4 + r2;
                float v = acc3[mt][nt][r2] + bias;
                v = (v > 0.f) ? v : 0.f;
                tile[row * 264 + col] = (short)f2bf(v);
            }
        }
    __syncthreads();

    // ================= stage 4: per-row head select, logits, softmax =================
    {
        int r = tid >> 3, is = tid & 7;
        int grow = blk0 + r;
        int kk = 2 * x[grow] + y[grow];
        short8 t8 = *(short8*)&tile[r * 264 + kk * 64 + is * 8];
        const float* wp = Wh2 + kk * 256 + is * 32;
        float lg0 = 0.f, lg1 = 0.f, lg2 = 0.f, lg3 = 0.f;
#pragma unroll
        for (int dd = 0; dd < 8; dd++) {
            float td = bf2f(t8[dd]);
            floatx4 wv = *(const floatx4*)(wp + dd * 4);
            lg0 += td * wv[0]; lg1 += td * wv[1]; lg2 += td * wv[2]; lg3 += td * wv[3];
        }
#pragma unroll
        for (int off = 1; off < 8; off <<= 1) {
            lg0 += __shfl_xor(lg0, off, 64);
            lg1 += __shfl_xor(lg1, off, 64);
            lg2 += __shfl_xor(lg2, off, 64);
            lg3 += __shfl_xor(lg3, off, 64);
        }
        if (is == 0) {
            lg0 += bh2[kk * 4 + 0]; lg1 += bh2[kk * 4 + 1];
            lg2 += bh2[kk * 4 + 2]; lg3 += bh2[kk * 4 + 3];
            float m = fmaxf(fmaxf(lg0, lg1), fmaxf(lg2, lg3));
            float e0 = __expf(lg0 - m), e1 = __expf(lg1 - m);
            float e2 = __expf(lg2 - m), e3 = __expf(lg3 - m);
            float inv = 1.f / (e0 + e1 + e2 + e3);
            floatx4 o = {e0 * inv, e1 * inv, e2 * inv, e3 * inv};
            *(floatx4*)(out + grow * 4) = o;
        }
    }
}

extern "C" void kernel_launch(void* const* d_in, const int* in_sizes, int n_in,
                              void* d_out, int out_size, void* d_ws, size_t ws_size,
                              hipStream_t stream) {
    const float* z   = (const float*)d_in[0];
    const int*   x   = (const int*)d_in[1];
    const int*   y   = (const int*)d_in[2];
    const float* W1  = (const float*)d_in[3];
    const float* b1  = (const float*)d_in[4];
    const float* g1  = (const float*)d_in[5];
    const float* be1 = (const float*)d_in[6];
    const float* W2  = (const float*)d_in[7];
    const float* b2  = (const float*)d_in[8];
    const float* g2  = (const float*)d_in[9];
    const float* be2 = (const float*)d_in[10];
    const float* Wh1 = (const float*)d_in[11];
    const float* bh1 = (const float*)d_in[12];
    const float* Wh2 = (const float*)d_in[13];
    const float* bh2 = (const float*)d_in[14];
    short* ws = (short*)d_ws;
    float* out = (float*)d_out;

    hipLaunchKernelGGL(convert_weights, dim3(1664), dim3(256), 0, stream, W1, W2, Wh1, ws);
    hipLaunchKernelGGL(fused_kernel, dim3(262144 / MT), dim3(256), 0, stream,
                       z, x, y, b1, g1, be1, b2, g2, be2, bh1, Wh2, bh2,
                       (const short*)ws, out);
}